// Round 4
// baseline (1211.537 us; speedup 1.0000x reference)
//
#include <hip/hip_runtime.h>
#include <hip/hip_bf16.h>

// Problem constants
constexpr int B_ = 32, S_ = 512, D_ = 512, H_ = 8, L_ = 4, F_ = 2048, DK_ = 64;

typedef __attribute__((ext_vector_type(8))) short short8;
typedef __attribute__((ext_vector_type(4))) float f32x4;

__device__ inline unsigned short f2b(float f) {
  union { __hip_bfloat16 h; unsigned short u; } cv;
  cv.h = __float2bfloat16(f);
  return cv.u;
}
__device__ inline float b2f(unsigned short u) {
  union { unsigned int i; float f; } c;
  c.i = ((unsigned int)u) << 16;
  return c.f;
}
__device__ inline float waveReduceSum(float v) {
  #pragma unroll
  for (int o = 32; o > 0; o >>= 1) v += __shfl_xor(v, o);
  return v;
}

// ---------------- prep: x = q + pos (f32 + bf16), y = qa + pos (bf16) --------
__global__ void prep_kernel(const float4* __restrict__ q, const float4* __restrict__ qa,
                            const float4* __restrict__ pos, float4* __restrict__ xf,
                            uint2* __restrict__ xb, uint2* __restrict__ yb) {
  int i = blockIdx.x * blockDim.x + threadIdx.x;  // 2,097,152 exact
  float4 p = pos[i & 65535];
  float4 a = q[i], c = qa[i];
  float4 xv, yv;
  xv.x = a.x + p.x; xv.y = a.y + p.y; xv.z = a.z + p.z; xv.w = a.w + p.w;
  yv.x = c.x + p.x; yv.y = c.y + p.y; yv.z = c.z + p.z; yv.w = c.w + p.w;
  xf[i] = xv;
  uint2 px, py;
  px.x = (unsigned)f2b(xv.x) | ((unsigned)f2b(xv.y) << 16);
  px.y = (unsigned)f2b(xv.z) | ((unsigned)f2b(xv.w) << 16);
  py.x = (unsigned)f2b(yv.x) | ((unsigned)f2b(yv.y) << 16);
  py.y = (unsigned)f2b(yv.z) | ((unsigned)f2b(yv.w) << 16);
  xb[i] = px;
  yb[i] = py;
}

// ---------------- cast fp32 -> bf16 ------------------------------------------
__global__ void cast_kernel(const float4* __restrict__ src, uint2* __restrict__ dst, int n4) {
  int i = blockIdx.x * blockDim.x + threadIdx.x;
  if (i >= n4) return;
  float4 v = src[i];
  uint2 p;
  p.x = (unsigned)f2b(v.x) | ((unsigned)f2b(v.y) << 16);
  p.y = (unsigned)f2b(v.z) | ((unsigned)f2b(v.w) << 16);
  dst[i] = p;
}

// ---------------- 256-col MFMA GEMM, stage-ahead double-buffered -------------
// C[M,N] = A[M,K] @ W[N,K]^T (+bias on z==0). BN=256, BK=64, 8 waves (2Mx4N).
// XCD-aware block swizzle; tile k+1 staged during compute of tile k.
// Epilogue: per-wave LDS re-layout -> fully coalesced 128B-per-row dwordx4
// bf16 stores. STORE: 0 = bf16 row-major (z picks Cb/Cb2), 2 = per-head
// transposed bf16 vT[((b*8+h)*64+d)*512 + t] (BM==128 only).
template<int BM, int RELU, int STORE>
__global__ __launch_bounds__(512, 2) void gemm256_kernel(
    const __hip_bfloat16* __restrict__ A,
    const __hip_bfloat16* __restrict__ W,
    const float* __restrict__ bias,
    __hip_bfloat16* __restrict__ Cb,
    __hip_bfloat16* __restrict__ Cb2,
    int Ndim, int Kdim, int kLen)
{
  constexpr int ABUF = BM * 128;   // bytes per A LDS buffer (BM x 64 bf16)
  constexpr int BBASE = 2 * ABUF;
  constexpr int M_REP = BM / 32;
  __shared__ char lds[BBASE + 65536];
  const int tid = threadIdx.x, wave = tid >> 6, lane = tid & 63;
  const int rl = lane & 15, gq = lane >> 4;
  const int wr = wave >> 2, wc = wave & 3;

  // XCD-aware bijective swizzle (nwg % 8 == 0 for all our grids)
  const int nwg = gridDim.x * gridDim.y;
  const int lin = blockIdx.y * gridDim.x + blockIdx.x;
  const int swz = (lin & 7) * (nwg >> 3) + (lin >> 3);
  const int bx = swz % gridDim.x, by = swz / gridDim.x;

  const int row0 = by * BM;
  const int col0 = bx * 256;
  const int kOff = blockIdx.z * kLen;

  f32x4 acc[M_REP][4] = {};
  const int ntiles = kLen >> 6;

  auto stage = [&](int kt, int d) {
    const int kbase = kOff + (kt << 6);
    #pragma unroll
    for (int r = 0; r < BM / 64; ++r) {
      int p = r * 8192 + wave * 1024 + lane * 16;
      int R = p >> 7, q = (p >> 4) & 7;
      int gc = q ^ (R & 7);
      const __hip_bfloat16* src = A + (size_t)(row0 + R) * Kdim + kbase + gc * 8;
      __builtin_amdgcn_global_load_lds(
          (const __attribute__((address_space(1))) void*)src,
          (__attribute__((address_space(3))) void*)(lds + d * ABUF + p), 16, 0, 0);
    }
    #pragma unroll
    for (int r = 0; r < 4; ++r) {
      int p = r * 8192 + wave * 1024 + lane * 16;
      int R = p >> 7, q = (p >> 4) & 7;
      int gc = q ^ (R & 7);
      const __hip_bfloat16* src = W + (size_t)(col0 + R) * Kdim + kbase + gc * 8;
      __builtin_amdgcn_global_load_lds(
          (const __attribute__((address_space(1))) void*)src,
          (__attribute__((address_space(3))) void*)(lds + BBASE + d * 32768 + p), 16, 0, 0);
    }
  };

  stage(0, 0);
  for (int kt = 0; kt < ntiles; ++kt) {
    const int d = kt & 1;
    asm volatile("s_waitcnt vmcnt(0)" ::: "memory");
    __builtin_amdgcn_sched_barrier(0);
    __syncthreads();
    if (kt + 1 < ntiles) stage(kt + 1, d ^ 1);
    __builtin_amdgcn_sched_barrier(0);

    #pragma unroll
    for (int ph = 0; ph < 4; ++ph) {
      constexpr int MH = M_REP / 2;
      const int mh = ph >> 1, nh = ph & 1;
      short8 aF[MH][2], bF[2][2];
      #pragma unroll
      for (int mi = 0; mi < MH; ++mi) {
        int r = wr * (BM / 2) + (mh * MH + mi) * 16 + rl;
        #pragma unroll
        for (int kf = 0; kf < 2; ++kf)
          aF[mi][kf] = *(const short8*)(lds + d * ABUF + r * 128 +
                                        (((kf * 4 + gq) ^ (r & 7)) << 4));
      }
      #pragma unroll
      for (int ni = 0; ni < 2; ++ni) {
        int r = wc * 64 + (nh * 2 + ni) * 16 + rl;
        #pragma unroll
        for (int kf = 0; kf < 2; ++kf)
          bF[ni][kf] = *(const short8*)(lds + BBASE + d * 32768 + r * 128 +
                                        (((kf * 4 + gq) ^ (r & 7)) << 4));
      }
      __builtin_amdgcn_s_setprio(1);
      #pragma unroll
      for (int mi = 0; mi < MH; ++mi)
        #pragma unroll
        for (int ni = 0; ni < 2; ++ni)
          #pragma unroll
          for (int kf = 0; kf < 2; ++kf)
            acc[mh * MH + mi][nh * 2 + ni] = __builtin_amdgcn_mfma_f32_16x16x32_bf16(
                aF[mi][kf], bF[ni][kf], acc[mh * MH + mi][nh * 2 + ni], 0, 0, 0);
      __builtin_amdgcn_s_setprio(0);
    }
  }

  // ---------------- coalesced epilogue (LDS re-layout) ----------------
  __syncthreads();  // all waves done with K-loop LDS buffers
  char* sw = lds + wave * (BM * 64);  // per-wave (BM/2 rows)*128B scratch
  const bool addb = (bias != nullptr) && (blockIdx.z == 0);
  float bvv[4];
  #pragma unroll
  for (int n = 0; n < 4; ++n)
    bvv[n] = addb ? bias[col0 + wc * 64 + n * 16 + rl] : 0.0f;

  #pragma unroll
  for (int n = 0; n < 4; ++n)
    #pragma unroll
    for (int m = 0; m < M_REP; ++m)
      #pragma unroll
      for (int j = 0; j < 4; ++j) {
        float val = acc[m][n][j] + bvv[n];
        if (RELU) val = fmaxf(val, 0.0f);
        int addr;
        if (STORE == 2) {
          int orow = n * 16 + rl, ocol = m * 16 + gq * 4 + j;
          addr = orow * 128 + ((ocol * 2) ^ ((orow & 7) << 4));
        } else {
          int orow = m * 16 + gq * 4 + j;
          addr = orow * 128 + (((n * 16 + rl) * 2) ^ (((orow >> 1) & 7) << 4));
        }
        *(unsigned short*)(sw + addr) = f2b(val);
      }
  asm volatile("s_waitcnt lgkmcnt(0)" ::: "memory");
  __builtin_amdgcn_sched_barrier(0);

  __hip_bfloat16* Cbd = blockIdx.z ? Cb2 : Cb;
  const int cchunk = lane & 7;
  if (STORE == 2) {
    // OUT tile: 64 d-rows x 64 t-cols (BM==128)
    const int bh64 = ((row0 >> 9) * 8 + (col0 >> 6) + wc) * 64;
    const int tbase = (row0 & 511) + wr * 64;
    #pragma unroll
    for (int it = 0; it < 8; ++it) {
      int d0 = it * 8 + (lane >> 3);
      uint4 vv = *(const uint4*)(sw + d0 * 128 + ((cchunk * 16) ^ ((d0 & 7) << 4)));
      *(uint4*)((char*)Cbd + ((size_t)(bh64 + d0) * 512 + tbase) * 2 + cchunk * 16) = vv;
    }
  } else {
    #pragma unroll
    for (int it = 0; it < BM / 16; ++it) {
      int orow = it * 8 + (lane >> 3);
      uint4 vv = *(const uint4*)(sw + orow * 128 + ((cchunk * 16) ^ (((orow >> 1) & 7) << 4)));
      *(uint4*)((char*)Cbd + ((size_t)(row0 + wr * (BM / 2) + orow) * Ndim + col0 + wc * 64) * 2 +
                cchunk * 16) = vv;
    }
  }
}

// ---------------- flash attention (MFMA, strict-causal, fr-scaled) -----------
// grid (S/128, B*H) with XCD swizzle; 4 waves; wave owns 32 q-rows. K/V tiles
// of 64 double-buffered in LDS (stage t+1 before compute t, vmcnt(4)).
__global__ __launch_bounds__(256, 4) void fattn_kernel(
    const __hip_bfloat16* __restrict__ kq,  // [B*S, D]
    const __hip_bfloat16* __restrict__ vT,  // [(b*8+h)*64+d][t]
    const float* __restrict__ fr,           // [B*S]
    __hip_bfloat16* __restrict__ ctx)       // [B*S, D]
{
  __shared__ char lds[40960];  // K0 K1 [0,16K), V0 V1 [16K,32K), P [32K,40K)
  const int tid = threadIdx.x, wave = tid >> 6, lane = tid & 63;
  const int rl = lane & 15, gq = lane >> 4;
  // XCD swizzle: blocks sharing bh land on one XCD (K/V L2-resident)
  const int lin = blockIdx.y * 4 + blockIdx.x;
  const int swz = (lin & 7) * 128 + (lin >> 3);
  const int qb = (swz & 3) * 128;
  const int bh = swz >> 2;
  const int b = bh >> 3, h = bh & 7;
  const size_t kqbase = ((size_t)b * S_) * D_ + h * DK_;
  const size_t vtbase = ((size_t)bh * DK_) * S_;
  const int qw0 = qb + wave * 32;
  const int qw_end = qw0 + 32;

  short8 qA[2][2];
  #pragma unroll
  for (int qf = 0; qf < 2; ++qf)
    #pragma unroll
    for (int kf = 0; kf < 2; ++kf)
      qA[qf][kf] = *(const short8*)(kq + kqbase + (size_t)(qw0 + qf * 16 + rl) * D_ + kf * 32 + gq * 8);

  float sfv[2][4];
  #pragma unroll
  for (int qf = 0; qf < 2; ++qf)
    #pragma unroll
    for (int j = 0; j < 4; ++j)
      sfv[qf][j] = fr[b * S_ + qw0 + qf * 16 + gq * 4 + j] * 0.125f;

  f32x4 o[2][4] = {};
  float mrow[2][4], lrow[2][4];
  #pragma unroll
  for (int qf = 0; qf < 2; ++qf)
    #pragma unroll
    for (int j = 0; j < 4; ++j) { mrow[qf][j] = -3.0e38f; lrow[qf][j] = 0.0f; }

  int sgoff[2], sldsoff[2];
  #pragma unroll
  for (int c = 0; c < 2; ++c) {
    int p = (wave * 2 + c) * 1024 + lane * 16;
    int r = p >> 7;
    int ch = (p >> 4) & 7;
    sgoff[c] = r * 1024 + ((ch ^ (r & 7)) << 4);
    sldsoff[c] = (wave * 2 + c) * 1024;
  }
  const char* kgbase = (const char*)kq + kqbase * 2;
  const char* vgbase = (const char*)vT + vtbase * 2;

  auto stage = [&](int ti, int d) {
    const int t0 = ti << 6;
    #pragma unroll
    for (int c = 0; c < 2; ++c) {
      __builtin_amdgcn_global_load_lds(
          (const __attribute__((address_space(1))) void*)(kgbase + (size_t)t0 * 1024 + sgoff[c]),
          (__attribute__((address_space(3))) void*)(lds + d * 8192 + sldsoff[c]), 16, 0, 0);
      __builtin_amdgcn_global_load_lds(
          (const __attribute__((address_space(1))) void*)(vgbase + t0 * 2 + sgoff[c]),
          (__attribute__((address_space(3))) void*)(lds + 16384 + d * 8192 + sldsoff[c]), 16, 0, 0);
    }
  };

  const int nt = (qb + 128) >> 6;
  stage(0, 0);
  for (int ti = 0; ti < nt; ++ti) {
    const int t0 = ti << 6;
    const int d = ti & 1;
    if (ti + 1 < nt) {
      stage(ti + 1, d ^ 1);
      asm volatile("s_waitcnt vmcnt(4)" ::: "memory");  // drain buf d, keep new 4
    } else {
      asm volatile("s_waitcnt vmcnt(0)" ::: "memory");
    }
    __builtin_amdgcn_sched_barrier(0);
    __syncthreads();

    if (t0 < qw_end) {
      short8 kB[4][2];
      #pragma unroll
      for (int tf = 0; tf < 4; ++tf)
        #pragma unroll
        for (int kf = 0; kf < 2; ++kf) {
          int r = tf * 16 + rl;
          kB[tf][kf] = *(const short8*)(lds + d * 8192 + r * 128 + (((kf * 4 + gq) ^ (r & 7)) << 4));
        }
      short8 vB[4][2];
      #pragma unroll
      for (int df = 0; df < 4; ++df)
        #pragma unroll
        for (int kf = 0; kf < 2; ++kf) {
          int r = df * 16 + rl;
          vB[df][kf] = *(const short8*)(lds + 16384 + d * 8192 + r * 128 + (((kf * 4 + gq) ^ (r & 7)) << 4));
        }

      #pragma unroll
      for (int qf = 0; qf < 2; ++qf) {
        f32x4 c4[4] = {};
        #pragma unroll
        for (int tf = 0; tf < 4; ++tf)
          #pragma unroll
          for (int kf = 0; kf < 2; ++kf)
            c4[tf] = __builtin_amdgcn_mfma_f32_16x16x32_bf16(qA[qf][kf], kB[tf][kf], c4[tf], 0, 0, 0);

        const int qg0 = qw0 + qf * 16 + gq * 4;
        #pragma unroll
        for (int tf = 0; tf < 4; ++tf) {
          int tg = t0 + tf * 16 + rl;
          #pragma unroll
          for (int j = 0; j < 4; ++j) {
            float s = c4[tf][j] * sfv[qf][j];
            c4[tf][j] = (tg >= qg0 + j) ? -3.0e38f : s;
          }
        }
        float tm[4];
        #pragma unroll
        for (int j = 0; j < 4; ++j) {
          tm[j] = fmaxf(fmaxf(c4[0][j], c4[1][j]), fmaxf(c4[2][j], c4[3][j]));
          #pragma unroll
          for (int msk = 1; msk < 16; msk <<= 1) tm[j] = fmaxf(tm[j], __shfl_xor(tm[j], msk));
        }
        #pragma unroll
        for (int j = 0; j < 4; ++j) {
          float mn = fmaxf(mrow[qf][j], tm[j]);
          float fac = __expf(mrow[qf][j] - mn);
          mrow[qf][j] = mn;
          lrow[qf][j] *= fac;
          #pragma unroll
          for (int df = 0; df < 4; ++df) o[qf][df][j] *= fac;
        }
        float rs[4] = {0.f, 0.f, 0.f, 0.f};
        #pragma unroll
        for (int tf = 0; tf < 4; ++tf) {
          int tloc = tf * 16 + rl;
          #pragma unroll
          for (int j = 0; j < 4; ++j) {
            float e = __expf(c4[tf][j] - mrow[qf][j]);
            rs[j] += e;
            int qloc = gq * 4 + j;
            int addr = 32768 + wave * 2048 + qloc * 128 +
                       ((((tloc >> 3) ^ (qloc & 7)) << 4)) + (tloc & 7) * 2;
            *(unsigned short*)(lds + addr) = f2b(e);
          }
        }
        #pragma unroll
        for (int j = 0; j < 4; ++j) {
          float r = rs[j];
          #pragma unroll
          for (int msk = 1; msk < 16; msk <<= 1) r += __shfl_xor(r, msk);
          lrow[qf][j] += r;
        }
        asm volatile("s_waitcnt lgkmcnt(0)" ::: "memory");
        __builtin_amdgcn_sched_barrier(0);
        short8 pA[2];
        #pragma unroll
        for (int kf = 0; kf < 2; ++kf)
          pA[kf] = *(const short8*)(lds + 32768 + wave * 2048 + rl * 128 +
                                    (((kf * 4 + gq) ^ (rl & 7)) << 4));
        #pragma unroll
        for (int df = 0; df < 4; ++df)
          #pragma unroll
          for (int kf = 0; kf < 2; ++kf)
            o[qf][df] = __builtin_amdgcn_mfma_f32_16x16x32_bf16(pA[kf], vB[df][kf], o[qf][df], 0, 0, 0);
      }
    }
    __syncthreads();
  }

  #pragma unroll
  for (int qf = 0; qf < 2; ++qf)
    #pragma unroll
    for (int j = 0; j < 4; ++j) {
      int qg = qw0 + qf * 16 + gq * 4 + j;
      float inv = (qg == 0) ? 0.0f : 1.0f / lrow[qf][j];
      #pragma unroll
      for (int df = 0; df < 4; ++df) {
        union { __hip_bfloat16 hh; unsigned short u; } cv;
        cv.u = f2b(o[qf][df][j] * inv);
        ctx[((size_t)(b * S_ + qg)) * D_ + h * DK_ + df * 16 + rl] = cv.hh;
      }
    }
}

// ---------------- fused residual + LayerNorm (wave per row) ------------------
// add / add2 are bf16 rows [512]; NADD==2 sums both (split-K combine).
template<int NADD>
__global__ __launch_bounds__(256) void ln_kernel(
    const float4* __restrict__ xin, const uint4* __restrict__ add,
    const uint4* __restrict__ add2,
    const float* __restrict__ g, const float* __restrict__ bta,
    float4* xf_out, uint2* __restrict__ xb_out)
{
  const int lane = threadIdx.x & 63, wv = threadIdx.x >> 6;
  const size_t row = (size_t)blockIdx.x * 4 + wv;
  const size_t base4 = row * 128;

  float4 x0 = xin[base4 + lane * 2], x1 = xin[base4 + lane * 2 + 1];
  uint4 ab = add[row * 64 + lane];
  const unsigned short* ap = (const unsigned short*)&ab;
  float v[8];
  v[0] = x0.x; v[1] = x0.y; v[2] = x0.z; v[3] = x0.w;
  v[4] = x1.x; v[5] = x1.y; v[6] = x1.z; v[7] = x1.w;
  #pragma unroll
  for (int i = 0; i < 8; ++i) v[i] += b2f(ap[i]);
  if (NADD == 2) {
    uint4 ab2 = add2[row * 64 + lane];
    const unsigned short* ap2 = (const unsigned short*)&ab2;
    #pragma unroll
    for (int i = 0; i < 8; ++i) v[i] += b2f(ap2[i]);
  }
  float s = 0.0f;
  #pragma unroll
  for (int i = 0; i < 8; ++i) s += v[i];
  s = waveReduceSum(s);
  float mu = s * (1.0f / 512.0f);
  float vs = 0.0f;
  #pragma unroll
  for (int i = 0; i < 8; ++i) { float dd = v[i] - mu; vs += dd * dd; }
  vs = waveReduceSum(vs);
  float rstd = rsqrtf(vs * (1.0f / 512.0f) + 1e-5f);

  const int c0i = lane * 8;
  float4 gg0 = *(const float4*)(g + c0i), gg1 = *(const float4*)(g + c0i + 4);
  float4 bb0 = *(const float4*)(bta + c0i), bb1 = *(const float4*)(bta + c0i + 4);
  float o[8];
  o[0] = (v[0] - mu) * rstd * gg0.x + bb0.x;
  o[1] = (v[1] - mu) * rstd * gg0.y + bb0.y;
  o[2] = (v[2] - mu) * rstd * gg0.z + bb0.z;
  o[3] = (v[3] - mu) * rstd * gg0.w + bb0.w;
  o[4] = (v[4] - mu) * rstd * gg1.x + bb1.x;
  o[5] = (v[5] - mu) * rstd * gg1.y + bb1.y;
  o[6] = (v[6] - mu) * rstd * gg1.z + bb1.z;
  o[7] = (v[7] - mu) * rstd * gg1.w + bb1.w;
  float4 w0, w1;
  w0.x = o[0]; w0.y = o[1]; w0.z = o[2]; w0.w = o[3];
  w1.x = o[4]; w1.y = o[5]; w1.z = o[6]; w1.w = o[7];
  xf_out[base4 + lane * 2] = w0;
  xf_out[base4 + lane * 2 + 1] = w1;
  uint2 p0, p1;
  p0.x = (unsigned)f2b(o[0]) | ((unsigned)f2b(o[1]) << 16);
  p0.y = (unsigned)f2b(o[2]) | ((unsigned)f2b(o[3]) << 16);
  p1.x = (unsigned)f2b(o[4]) | ((unsigned)f2b(o[5]) << 16);
  p1.y = (unsigned)f2b(o[6]) | ((unsigned)f2b(o[7]) << 16);
  xb_out[row * 128 + lane * 2] = p0;
  xb_out[row * 128 + lane * 2 + 1] = p1;
}

// ---------------- launcher ---------------------------------------------------
extern "C" void kernel_launch(void* const* d_in, const int* in_sizes, int n_in,
                              void* d_out, int out_size, void* d_ws, size_t ws_size,
                              hipStream_t stream) {
  (void)in_sizes; (void)n_in; (void)out_size; (void)ws_size;
  const float* q   = (const float*)d_in[0];
  const float* qa  = (const float*)d_in[1];
  const float* frr = (const float*)d_in[2];
  const float* pos = (const float*)d_in[3];
  const float* Wk  = (const float*)d_in[4];
  const float* bk  = (const float*)d_in[5];
  const float* Wv  = (const float*)d_in[6];
  const float* bv  = (const float*)d_in[7];
  const float* Wo  = (const float*)d_in[8];
  const float* bo  = (const float*)d_in[9];
  const float* W1  = (const float*)d_in[10];
  const float* b1  = (const float*)d_in[11];
  const float* W2  = (const float*)d_in[12];
  const float* b2  = (const float*)d_in[13];
  const float* g1  = (const float*)d_in[14];
  const float* be1 = (const float*)d_in[15];
  const float* g2  = (const float*)d_in[16];
  const float* be2 = (const float*)d_in[17];

  char* ws = (char*)d_ws;
  float*          xf   = (float*)(ws + 0);                      // 33.5 MB
  __hip_bfloat16* xb   = (__hip_bfloat16*)(ws + 33554432);
  __hip_bfloat16* yb   = (__hip_bfloat16*)(ws + 50331648);
  __hip_bfloat16* kqb  = (__hip_bfloat16*)(ws + 67108864);
  __hip_bfloat16* vtb  = (__hip_bfloat16*)(ws + 83886080);
  __hip_bfloat16* ctxb = (__hip_bfloat16*)(ws + 100663296);
  __hip_bfloat16* hb   = (__hip_bfloat16*)(ws + 117440512);     // 67.1 MB
  __hip_bfloat16* wkb  = (__hip_bfloat16*)(ws + 184549376);
  __hip_bfloat16* wvb  = (__hip_bfloat16*)(ws + 186646528);
  __hip_bfloat16* wob  = (__hip_bfloat16*)(ws + 188743680);
  __hip_bfloat16* w1b  = (__hip_bfloat16*)(ws + 190840832);
  __hip_bfloat16* w2b  = (__hip_bfloat16*)(ws + 199229440);
  // dead-region reuse (per-layer lifetimes):
  __hip_bfloat16* obf = (__hip_bfloat16*)(ws + 67108864);   // over kqb (dead post-fattn)
  __hip_bfloat16* pf0 = (__hip_bfloat16*)(ws + 83886080);   // over vtb (dead post-fattn)
  __hip_bfloat16* pf1 = (__hip_bfloat16*)(ws + 100663296);  // over ctxb (dead post-projO)

  prep_kernel<<<8192, 256, 0, stream>>>((const float4*)q, (const float4*)qa,
                                        (const float4*)pos, (float4*)xf,
                                        (uint2*)xb, (uint2*)yb);
  cast_kernel<<<1024, 256, 0, stream>>>((const float4*)Wk, (uint2*)wkb, 262144);
  cast_kernel<<<1024, 256, 0, stream>>>((const float4*)Wv, (uint2*)wvb, 262144);
  cast_kernel<<<1024, 256, 0, stream>>>((const float4*)Wo, (uint2*)wob, 262144);
  cast_kernel<<<4096, 256, 0, stream>>>((const float4*)W1, (uint2*)w1b, 1048576);
  cast_kernel<<<4096, 256, 0, stream>>>((const float4*)W2, (uint2*)w2b, 1048576);

  for (int l = 0; l < L_; ++l) {
    gemm256_kernel<128,0,0><<<dim3(2, 128, 1), 512, 0, stream>>>(
        xb, wkb + (size_t)l * 262144, bk + l * 512, kqb, nullptr, 512, 512, 512);
    gemm256_kernel<128,0,2><<<dim3(2, 128, 1), 512, 0, stream>>>(
        yb, wvb + (size_t)l * 262144, bv + l * 512, vtb, nullptr, 512, 512, 512);
    fattn_kernel<<<dim3(4, 256), 256, 0, stream>>>(kqb, vtb, frr, ctxb);
    gemm256_kernel<128,0,0><<<dim3(2, 128, 1), 512, 0, stream>>>(
        ctxb, wob + (size_t)l * 262144, bo + l * 512, obf, nullptr, 512, 512, 512);
    ln_kernel<1><<<4096, 256, 0, stream>>>((const float4*)xf, (const uint4*)obf, nullptr,
                                           g1 + l * 512, be1 + l * 512,
                                           (float4*)xf, (uint2*)xb);
    gemm256_kernel<256,1,0><<<dim3(8, 64, 1), 512, 0, stream>>>(
        xb, w1b + (size_t)l * 1048576, b1 + l * 2048, hb, nullptr, 2048, 512, 512);
    gemm256_kernel<256,0,0><<<dim3(2, 64, 2), 512, 0, stream>>>(
        hb, w2b + (size_t)l * 1048576, b2 + l * 512, pf0, pf1, 512, 2048, 1024);
    float* lnout = (l == L_ - 1) ? (float*)d_out : xf;
    ln_kernel<2><<<4096, 256, 0, stream>>>((const float4*)xf, (const uint4*)pf0,
                                           (const uint4*)pf1,
                                           g2 + l * 512, be2 + l * 512,
                                           (float4*)lnout, (uint2*)xb);
  }
}

// Round 5
// 824.252 us; speedup vs baseline: 1.4699x; 1.4699x over previous
//
#include <hip/hip_runtime.h>
#include <hip/hip_bf16.h>

// Problem constants
constexpr int B_ = 32, S_ = 512, D_ = 512, H_ = 8, L_ = 4, F_ = 2048, DK_ = 64;

typedef __attribute__((ext_vector_type(8))) short short8;
typedef __attribute__((ext_vector_type(4))) float f32x4;

__device__ inline unsigned short f2b(float f) {
  union { __hip_bfloat16 h; unsigned short u; } cv;
  cv.h = __float2bfloat16(f);
  return cv.u;
}
__device__ inline float b2f(unsigned short u) {
  union { unsigned int i; float f; } c;
  c.i = ((unsigned int)u) << 16;
  return c.f;
}
__device__ inline float waveReduceSum(float v) {
  #pragma unroll
  for (int o = 32; o > 0; o >>= 1) v += __shfl_xor(v, o);
  return v;
}

// ---------------- prep: x = q + pos (f32 + bf16), y = qa + pos (bf16) --------
__global__ void prep_kernel(const float4* __restrict__ q, const float4* __restrict__ qa,
                            const float4* __restrict__ pos, float4* __restrict__ xf,
                            uint2* __restrict__ xb, uint2* __restrict__ yb) {
  int i = blockIdx.x * blockDim.x + threadIdx.x;  // 2,097,152 exact
  float4 p = pos[i & 65535];
  float4 a = q[i], c = qa[i];
  float4 xv, yv;
  xv.x = a.x + p.x; xv.y = a.y + p.y; xv.z = a.z + p.z; xv.w = a.w + p.w;
  yv.x = c.x + p.x; yv.y = c.y + p.y; yv.z = c.z + p.z; yv.w = c.w + p.w;
  xf[i] = xv;
  uint2 px, py;
  px.x = (unsigned)f2b(xv.x) | ((unsigned)f2b(xv.y) << 16);
  px.y = (unsigned)f2b(xv.z) | ((unsigned)f2b(xv.w) << 16);
  py.x = (unsigned)f2b(yv.x) | ((unsigned)f2b(yv.y) << 16);
  py.y = (unsigned)f2b(yv.z) | ((unsigned)f2b(yv.w) << 16);
  xb[i] = px;
  yb[i] = py;
}

// ---------------- cast fp32 -> bf16 ------------------------------------------
__global__ void cast_kernel(const float4* __restrict__ src, uint2* __restrict__ dst, int n4) {
  int i = blockIdx.x * blockDim.x + threadIdx.x;
  if (i >= n4) return;
  float4 v = src[i];
  uint2 p;
  p.x = (unsigned)f2b(v.x) | ((unsigned)f2b(v.y) << 16);
  p.y = (unsigned)f2b(v.z) | ((unsigned)f2b(v.w) << 16);
  dst[i] = p;
}

// ---------------- 256-col MFMA GEMM, stage-ahead double-buffered -------------
// C[M,N] = A[M,K] @ W[N,K]^T. BN=256, BK=64, 8 waves (2Mx4N). XCD swizzle.
// Coalesced epilogue via per-wave LDS re-layout.
// STORE 0: bf16 row-major; z picks Cb/Cb2 (split-K partials, bias only z==0).
// STORE 2: per-head transposed vT[((b*8+h)*64+d)*512+t] (BM==128 only).
// STORE 3: fused dual-GEMM — z==0: A/W/bias -> Cb row-major;
//                            z==1: A2/W2/bias2 -> Cb2 vT-transposed.
template<int BM, int RELU, int STORE>
__global__ __launch_bounds__(512, 2) void gemm256_kernel(
    const __hip_bfloat16* __restrict__ A,
    const __hip_bfloat16* __restrict__ W,
    const float* __restrict__ bias,
    const __hip_bfloat16* __restrict__ A2,
    const __hip_bfloat16* __restrict__ W2,
    const float* __restrict__ bias2,
    __hip_bfloat16* __restrict__ Cb,
    __hip_bfloat16* __restrict__ Cb2,
    int Ndim, int Kdim, int kLen)
{
  constexpr int ABUF = BM * 128;   // bytes per A LDS buffer (BM x 64 bf16)
  constexpr int BBASE = 2 * ABUF;
  constexpr int M_REP = BM / 32;
  __shared__ char lds[BBASE + 65536];
  const int tid = threadIdx.x, wave = tid >> 6, lane = tid & 63;
  const int rl = lane & 15, gq = lane >> 4;
  const int wr = wave >> 2, wc = wave & 3;

  // XCD-aware bijective swizzle (nwg % 8 == 0 for all our grids)
  const int nwg = gridDim.x * gridDim.y;
  const int lin = blockIdx.y * gridDim.x + blockIdx.x;
  const int swz = (lin & 7) * (nwg >> 3) + (lin >> 3);
  const int bx = swz % gridDim.x, by = swz / gridDim.x;

  const int row0 = by * BM;
  const int col0 = bx * 256;

  const __hip_bfloat16* Ap = A;
  const __hip_bfloat16* Wp = W;
  const float* bp = bias;
  int kOff = blockIdx.z * kLen;
  if (STORE == 3) {
    kOff = 0;
    if (blockIdx.z) { Ap = A2; Wp = W2; bp = bias2; }
  }

  f32x4 acc[M_REP][4] = {};
  const int ntiles = kLen >> 6;

  auto stage = [&](int kt, int d) {
    const int kbase = kOff + (kt << 6);
    #pragma unroll
    for (int r = 0; r < BM / 64; ++r) {
      int p = r * 8192 + wave * 1024 + lane * 16;
      int R = p >> 7, q = (p >> 4) & 7;
      int gc = q ^ (R & 7);
      const __hip_bfloat16* src = Ap + (size_t)(row0 + R) * Kdim + kbase + gc * 8;
      __builtin_amdgcn_global_load_lds(
          (const __attribute__((address_space(1))) void*)src,
          (__attribute__((address_space(3))) void*)(lds + d * ABUF + p), 16, 0, 0);
    }
    #pragma unroll
    for (int r = 0; r < 4; ++r) {
      int p = r * 8192 + wave * 1024 + lane * 16;
      int R = p >> 7, q = (p >> 4) & 7;
      int gc = q ^ (R & 7);
      const __hip_bfloat16* src = Wp + (size_t)(col0 + R) * Kdim + kbase + gc * 8;
      __builtin_amdgcn_global_load_lds(
          (const __attribute__((address_space(1))) void*)src,
          (__attribute__((address_space(3))) void*)(lds + BBASE + d * 32768 + p), 16, 0, 0);
    }
  };

  stage(0, 0);
  for (int kt = 0; kt < ntiles; ++kt) {
    const int d = kt & 1;
    asm volatile("s_waitcnt vmcnt(0)" ::: "memory");
    __builtin_amdgcn_sched_barrier(0);
    __syncthreads();
    if (kt + 1 < ntiles) stage(kt + 1, d ^ 1);
    __builtin_amdgcn_sched_barrier(0);

    #pragma unroll
    for (int ph = 0; ph < 4; ++ph) {
      constexpr int MH = M_REP / 2;
      const int mh = ph >> 1, nh = ph & 1;
      short8 aF[MH][2], bF[2][2];
      #pragma unroll
      for (int mi = 0; mi < MH; ++mi) {
        int r = wr * (BM / 2) + (mh * MH + mi) * 16 + rl;
        #pragma unroll
        for (int kf = 0; kf < 2; ++kf)
          aF[mi][kf] = *(const short8*)(lds + d * ABUF + r * 128 +
                                        (((kf * 4 + gq) ^ (r & 7)) << 4));
      }
      #pragma unroll
      for (int ni = 0; ni < 2; ++ni) {
        int r = wc * 64 + (nh * 2 + ni) * 16 + rl;
        #pragma unroll
        for (int kf = 0; kf < 2; ++kf)
          bF[ni][kf] = *(const short8*)(lds + BBASE + d * 32768 + r * 128 +
                                        (((kf * 4 + gq) ^ (r & 7)) << 4));
      }
      __builtin_amdgcn_s_setprio(1);
      #pragma unroll
      for (int mi = 0; mi < MH; ++mi)
        #pragma unroll
        for (int ni = 0; ni < 2; ++ni)
          #pragma unroll
          for (int kf = 0; kf < 2; ++kf)
            acc[mh * MH + mi][nh * 2 + ni] = __builtin_amdgcn_mfma_f32_16x16x32_bf16(
                aF[mi][kf], bF[ni][kf], acc[mh * MH + mi][nh * 2 + ni], 0, 0, 0);
      __builtin_amdgcn_s_setprio(0);
    }
  }

  // ---------------- coalesced epilogue (LDS re-layout) ----------------
  __syncthreads();  // all waves done with K-loop LDS buffers
  char* sw = lds + wave * (BM * 64);  // per-wave (BM/2 rows)*128B scratch
  const bool vt = (STORE == 2) || (STORE == 3 && blockIdx.z == 1);
  const bool addb = (STORE == 3) ? true : ((bias != nullptr) && (blockIdx.z == 0));
  float bvv[4];
  #pragma unroll
  for (int n = 0; n < 4; ++n)
    bvv[n] = addb ? bp[col0 + wc * 64 + n * 16 + rl] : 0.0f;

  #pragma unroll
  for (int n = 0; n < 4; ++n)
    #pragma unroll
    for (int m = 0; m < M_REP; ++m)
      #pragma unroll
      for (int j = 0; j < 4; ++j) {
        float val = acc[m][n][j] + bvv[n];
        if (RELU) val = fmaxf(val, 0.0f);
        int addr;
        if (vt) {
          int orow = n * 16 + rl, ocol = m * 16 + gq * 4 + j;
          addr = orow * 128 + ((ocol * 2) ^ ((orow & 7) << 4));
        } else {
          int orow = m * 16 + gq * 4 + j;
          addr = orow * 128 + (((n * 16 + rl) * 2) ^ (((orow >> 1) & 7) << 4));
        }
        *(unsigned short*)(sw + addr) = f2b(val);
      }
  asm volatile("s_waitcnt lgkmcnt(0)" ::: "memory");
  __builtin_amdgcn_sched_barrier(0);

  __hip_bfloat16* Cbd = blockIdx.z ? Cb2 : Cb;
  const int cchunk = lane & 7;
  if (vt) {
    // OUT tile: 64 d-rows x 64 t-cols (BM==128)
    const int bh64 = ((row0 >> 9) * 8 + (col0 >> 6) + wc) * 64;
    const int tbase = (row0 & 511) + wr * 64;
    #pragma unroll
    for (int it = 0; it < 8; ++it) {
      int d0 = it * 8 + (lane >> 3);
      uint4 vv = *(const uint4*)(sw + d0 * 128 + ((cchunk * 16) ^ ((d0 & 7) << 4)));
      *(uint4*)((char*)Cbd + ((size_t)(bh64 + d0) * 512 + tbase) * 2 + cchunk * 16) = vv;
    }
  } else {
    #pragma unroll
    for (int it = 0; it < BM / 16; ++it) {
      int orow = it * 8 + (lane >> 3);
      uint4 vv = *(const uint4*)(sw + orow * 128 + ((cchunk * 16) ^ (((orow >> 1) & 7) << 4)));
      *(uint4*)((char*)Cbd + ((size_t)(row0 + wr * (BM / 2) + orow) * Ndim + col0 + wc * 64) * 2 +
                cchunk * 16) = vv;
    }
  }
}

// ---------------- flash attention (MFMA, strict-causal, fr-scaled) -----------
// grid 1024 1D. phase = lin>>8 maps to q-block (heavy first); wpi = lin&255
// maps to bh (XCD-chunked). Breadth-first dispatch puts all 4 q-blocks of one
// bh on the same CU (blocks c, c+256, c+512, c+768): uniform per-CU work
// (2+4+6+8 K-tiles) and K/V L1/L2 reuse. K/V tiles of 64 double-buffered.
__global__ __launch_bounds__(256, 2) void fattn_kernel(
    const __hip_bfloat16* __restrict__ kq,  // [B*S, D]
    const __hip_bfloat16* __restrict__ vT,  // [(b*8+h)*64+d][t]
    const float* __restrict__ fr,           // [B*S]
    __hip_bfloat16* __restrict__ ctx)       // [B*S, D]
{
  __shared__ char lds[40960];  // K0 K1 [0,16K), V0 V1 [16K,32K), P [32K,40K)
  const int tid = threadIdx.x, wave = tid >> 6, lane = tid & 63;
  const int rl = lane & 15, gq = lane >> 4;
  const int lin = blockIdx.x;
  const int qb = (3 - (lin >> 8)) * 128;             // heavy q-blocks first
  const int wpi = lin & 255;
  const int bh = (wpi & 7) * 32 + (wpi >> 3);        // XCD-chunked bh
  const int b = bh >> 3, h = bh & 7;
  const size_t kqbase = ((size_t)b * S_) * D_ + h * DK_;
  const size_t vtbase = ((size_t)bh * DK_) * S_;
  const int qw0 = qb + wave * 32;
  const int qw_end = qw0 + 32;

  short8 qA[2][2];
  #pragma unroll
  for (int qf = 0; qf < 2; ++qf)
    #pragma unroll
    for (int kf = 0; kf < 2; ++kf)
      qA[qf][kf] = *(const short8*)(kq + kqbase + (size_t)(qw0 + qf * 16 + rl) * D_ + kf * 32 + gq * 8);

  float sfv[2][4];
  #pragma unroll
  for (int qf = 0; qf < 2; ++qf)
    #pragma unroll
    for (int j = 0; j < 4; ++j)
      sfv[qf][j] = fr[b * S_ + qw0 + qf * 16 + gq * 4 + j] * 0.125f;

  f32x4 o[2][4] = {};
  float mrow[2][4], lrow[2][4];
  #pragma unroll
  for (int qf = 0; qf < 2; ++qf)
    #pragma unroll
    for (int j = 0; j < 4; ++j) { mrow[qf][j] = -3.0e38f; lrow[qf][j] = 0.0f; }

  int sgoff[2], sldsoff[2];
  #pragma unroll
  for (int c = 0; c < 2; ++c) {
    int p = (wave * 2 + c) * 1024 + lane * 16;
    int r = p >> 7;
    int ch = (p >> 4) & 7;
    sgoff[c] = r * 1024 + ((ch ^ (r & 7)) << 4);
    sldsoff[c] = (wave * 2 + c) * 1024;
  }
  const char* kgbase = (const char*)kq + kqbase * 2;
  const char* vgbase = (const char*)vT + vtbase * 2;

  auto stage = [&](int ti, int d) {
    const int t0 = ti << 6;
    #pragma unroll
    for (int c = 0; c < 2; ++c) {
      __builtin_amdgcn_global_load_lds(
          (const __attribute__((address_space(1))) void*)(kgbase + (size_t)t0 * 1024 + sgoff[c]),
          (__attribute__((address_space(3))) void*)(lds + d * 8192 + sldsoff[c]), 16, 0, 0);
      __builtin_amdgcn_global_load_lds(
          (const __attribute__((address_space(1))) void*)(vgbase + t0 * 2 + sgoff[c]),
          (__attribute__((address_space(3))) void*)(lds + 16384 + d * 8192 + sldsoff[c]), 16, 0, 0);
    }
  };

  const int nt = (qb + 128) >> 6;
  stage(0, 0);
  for (int ti = 0; ti < nt; ++ti) {
    const int t0 = ti << 6;
    const int d = ti & 1;
    if (ti + 1 < nt) {
      stage(ti + 1, d ^ 1);
      asm volatile("s_waitcnt vmcnt(4)" ::: "memory");  // drain buf d, keep new 4
    } else {
      asm volatile("s_waitcnt vmcnt(0)" ::: "memory");
    }
    __builtin_amdgcn_sched_barrier(0);
    __syncthreads();

    if (t0 < qw_end) {
      short8 kB[4][2];
      #pragma unroll
      for (int tf = 0; tf < 4; ++tf)
        #pragma unroll
        for (int kf = 0; kf < 2; ++kf) {
          int r = tf * 16 + rl;
          kB[tf][kf] = *(const short8*)(lds + d * 8192 + r * 128 + (((kf * 4 + gq) ^ (r & 7)) << 4));
        }
      short8 vB[4][2];
      #pragma unroll
      for (int df = 0; df < 4; ++df)
        #pragma unroll
        for (int kf = 0; kf < 2; ++kf) {
          int r = df * 16 + rl;
          vB[df][kf] = *(const short8*)(lds + 16384 + d * 8192 + r * 128 + (((kf * 4 + gq) ^ (r & 7)) << 4));
        }

      #pragma unroll
      for (int qf = 0; qf < 2; ++qf) {
        f32x4 c4[4] = {};
        #pragma unroll
        for (int tf = 0; tf < 4; ++tf)
          #pragma unroll
          for (int kf = 0; kf < 2; ++kf)
            c4[tf] = __builtin_amdgcn_mfma_f32_16x16x32_bf16(qA[qf][kf], kB[tf][kf], c4[tf], 0, 0, 0);

        const int qg0 = qw0 + qf * 16 + gq * 4;
        #pragma unroll
        for (int tf = 0; tf < 4; ++tf) {
          int tg = t0 + tf * 16 + rl;
          #pragma unroll
          for (int j = 0; j < 4; ++j) {
            float s = c4[tf][j] * sfv[qf][j];
            c4[tf][j] = (tg >= qg0 + j) ? -3.0e38f : s;
          }
        }
        float tm[4];
        #pragma unroll
        for (int j = 0; j < 4; ++j) {
          tm[j] = fmaxf(fmaxf(c4[0][j], c4[1][j]), fmaxf(c4[2][j], c4[3][j]));
          #pragma unroll
          for (int msk = 1; msk < 16; msk <<= 1) tm[j] = fmaxf(tm[j], __shfl_xor(tm[j], msk));
        }
        #pragma unroll
        for (int j = 0; j < 4; ++j) {
          float mn = fmaxf(mrow[qf][j], tm[j]);
          float fac = __expf(mrow[qf][j] - mn);
          mrow[qf][j] = mn;
          lrow[qf][j] *= fac;
          #pragma unroll
          for (int df = 0; df < 4; ++df) o[qf][df][j] *= fac;
        }
        float rs[4] = {0.f, 0.f, 0.f, 0.f};
        #pragma unroll
        for (int tf = 0; tf < 4; ++tf) {
          int tloc = tf * 16 + rl;
          #pragma unroll
          for (int j = 0; j < 4; ++j) {
            float e = __expf(c4[tf][j] - mrow[qf][j]);
            rs[j] += e;
            int qloc = gq * 4 + j;
            int addr = 32768 + wave * 2048 + qloc * 128 +
                       ((((tloc >> 3) ^ (qloc & 7)) << 4)) + (tloc & 7) * 2;
            *(unsigned short*)(lds + addr) = f2b(e);
          }
        }
        #pragma unroll
        for (int j = 0; j < 4; ++j) {
          float r = rs[j];
          #pragma unroll
          for (int msk = 1; msk < 16; msk <<= 1) r += __shfl_xor(r, msk);
          lrow[qf][j] += r;
        }
        asm volatile("s_waitcnt lgkmcnt(0)" ::: "memory");
        __builtin_amdgcn_sched_barrier(0);
        short8 pA[2];
        #pragma unroll
        for (int kf = 0; kf < 2; ++kf)
          pA[kf] = *(const short8*)(lds + 32768 + wave * 2048 + rl * 128 +
                                    (((kf * 4 + gq) ^ (rl & 7)) << 4));
        #pragma unroll
        for (int df = 0; df < 4; ++df)
          #pragma unroll
          for (int kf = 0; kf < 2; ++kf)
            o[qf][df] = __builtin_amdgcn_mfma_f32_16x16x32_bf16(pA[kf], vB[df][kf], o[qf][df], 0, 0, 0);
      }
    }
    __syncthreads();
  }

  #pragma unroll
  for (int qf = 0; qf < 2; ++qf)
    #pragma unroll
    for (int j = 0; j < 4; ++j) {
      int qg = qw0 + qf * 16 + gq * 4 + j;
      float inv = (qg == 0) ? 0.0f : 1.0f / lrow[qf][j];
      #pragma unroll
      for (int df = 0; df < 4; ++df) {
        union { __hip_bfloat16 hh; unsigned short u; } cv;
        cv.u = f2b(o[qf][df][j] * inv);
        ctx[((size_t)(b * S_ + qg)) * D_ + h * DK_ + df * 16 + rl] = cv.hh;
      }
    }
}

// ---------------- fused residual + LayerNorm (wave per row) ------------------
// add / add2 are bf16 rows [512]; NADD==2 sums both (split-K combine).
template<int NADD>
__global__ __launch_bounds__(256) void ln_kernel(
    const float4* __restrict__ xin, const uint4* __restrict__ add,
    const uint4* __restrict__ add2,
    const float* __restrict__ g, const float* __restrict__ bta,
    float4* xf_out, uint2* __restrict__ xb_out)
{
  const int lane = threadIdx.x & 63, wv = threadIdx.x >> 6;
  const size_t row = (size_t)blockIdx.x * 4 + wv;
  const size_t base4 = row * 128;

  float4 x0 = xin[base4 + lane * 2], x1 = xin[base4 + lane * 2 + 1];
  uint4 ab = add[row * 64 + lane];
  const unsigned short* ap = (const unsigned short*)&ab;
  float v[8];
  v[0] = x0.x; v[1] = x0.y; v[2] = x0.z; v[3] = x0.w;
  v[4] = x1.x; v[5] = x1.y; v[6] = x1.z; v[7] = x1.w;
  #pragma unroll
  for (int i = 0; i < 8; ++i) v[i] += b2f(ap[i]);
  if (NADD == 2) {
    uint4 ab2 = add2[row * 64 + lane];
    const unsigned short* ap2 = (const unsigned short*)&ab2;
    #pragma unroll
    for (int i = 0; i < 8; ++i) v[i] += b2f(ap2[i]);
  }
  float s = 0.0f;
  #pragma unroll
  for (int i = 0; i < 8; ++i) s += v[i];
  s = waveReduceSum(s);
  float mu = s * (1.0f / 512.0f);
  float vs = 0.0f;
  #pragma unroll
  for (int i = 0; i < 8; ++i) { float dd = v[i] - mu; vs += dd * dd; }
  vs = waveReduceSum(vs);
  float rstd = rsqrtf(vs * (1.0f / 512.0f) + 1e-5f);

  const int c0i = lane * 8;
  float4 gg0 = *(const float4*)(g + c0i), gg1 = *(const float4*)(g + c0i + 4);
  float4 bb0 = *(const float4*)(bta + c0i), bb1 = *(const float4*)(bta + c0i + 4);
  float o[8];
  o[0] = (v[0] - mu) * rstd * gg0.x + bb0.x;
  o[1] = (v[1] - mu) * rstd * gg0.y + bb0.y;
  o[2] = (v[2] - mu) * rstd * gg0.z + bb0.z;
  o[3] = (v[3] - mu) * rstd * gg0.w + bb0.w;
  o[4] = (v[4] - mu) * rstd * gg1.x + bb1.x;
  o[5] = (v[5] - mu) * rstd * gg1.y + bb1.y;
  o[6] = (v[6] - mu) * rstd * gg1.z + bb1.z;
  o[7] = (v[7] - mu) * rstd * gg1.w + bb1.w;
  float4 w0, w1;
  w0.x = o[0]; w0.y = o[1]; w0.z = o[2]; w0.w = o[3];
  w1.x = o[4]; w1.y = o[5]; w1.z = o[6]; w1.w = o[7];
  xf_out[base4 + lane * 2] = w0;
  xf_out[base4 + lane * 2 + 1] = w1;
  uint2 p0, p1;
  p0.x = (unsigned)f2b(o[0]) | ((unsigned)f2b(o[1]) << 16);
  p0.y = (unsigned)f2b(o[2]) | ((unsigned)f2b(o[3]) << 16);
  p1.x = (unsigned)f2b(o[4]) | ((unsigned)f2b(o[5]) << 16);
  p1.y = (unsigned)f2b(o[6]) | ((unsigned)f2b(o[7]) << 16);
  xb_out[row * 128 + lane * 2] = p0;
  xb_out[row * 128 + lane * 2 + 1] = p1;
}

// ---------------- launcher ---------------------------------------------------
extern "C" void kernel_launch(void* const* d_in, const int* in_sizes, int n_in,
                              void* d_out, int out_size, void* d_ws, size_t ws_size,
                              hipStream_t stream) {
  (void)in_sizes; (void)n_in; (void)out_size; (void)ws_size;
  const float* q   = (const float*)d_in[0];
  const float* qa  = (const float*)d_in[1];
  const float* frr = (const float*)d_in[2];
  const float* pos = (const float*)d_in[3];
  const float* Wk  = (const float*)d_in[4];
  const float* bk  = (const float*)d_in[5];
  const float* Wv  = (const float*)d_in[6];
  const float* bv  = (const float*)d_in[7];
  const float* Wo  = (const float*)d_in[8];
  const float* bo  = (const float*)d_in[9];
  const float* W1  = (const float*)d_in[10];
  const float* b1  = (const float*)d_in[11];
  const float* W2  = (const float*)d_in[12];
  const float* b2  = (const float*)d_in[13];
  const float* g1  = (const float*)d_in[14];
  const float* be1 = (const float*)d_in[15];
  const float* g2  = (const float*)d_in[16];
  const float* be2 = (const float*)d_in[17];

  char* ws = (char*)d_ws;
  float*          xf   = (float*)(ws + 0);                      // 33.5 MB
  __hip_bfloat16* xb   = (__hip_bfloat16*)(ws + 33554432);
  __hip_bfloat16* yb   = (__hip_bfloat16*)(ws + 50331648);
  __hip_bfloat16* kqb  = (__hip_bfloat16*)(ws + 67108864);
  __hip_bfloat16* vtb  = (__hip_bfloat16*)(ws + 83886080);
  __hip_bfloat16* ctxb = (__hip_bfloat16*)(ws + 100663296);
  __hip_bfloat16* hb   = (__hip_bfloat16*)(ws + 117440512);     // 67.1 MB
  __hip_bfloat16* wkb  = (__hip_bfloat16*)(ws + 184549376);
  __hip_bfloat16* wvb  = (__hip_bfloat16*)(ws + 186646528);
  __hip_bfloat16* wob  = (__hip_bfloat16*)(ws + 188743680);
  __hip_bfloat16* w1b  = (__hip_bfloat16*)(ws + 190840832);
  __hip_bfloat16* w2b  = (__hip_bfloat16*)(ws + 199229440);
  // dead-region reuse (per-layer lifetimes):
  __hip_bfloat16* obf = (__hip_bfloat16*)(ws + 67108864);   // over kqb (dead post-fattn)
  __hip_bfloat16* pf0 = (__hip_bfloat16*)(ws + 83886080);   // over vtb (dead post-fattn)
  __hip_bfloat16* pf1 = (__hip_bfloat16*)(ws + 100663296);  // over ctxb (dead post-projO)

  prep_kernel<<<8192, 256, 0, stream>>>((const float4*)q, (const float4*)qa,
                                        (const float4*)pos, (float4*)xf,
                                        (uint2*)xb, (uint2*)yb);
  cast_kernel<<<1024, 256, 0, stream>>>((const float4*)Wk, (uint2*)wkb, 262144);
  cast_kernel<<<1024, 256, 0, stream>>>((const float4*)Wv, (uint2*)wvb, 262144);
  cast_kernel<<<1024, 256, 0, stream>>>((const float4*)Wo, (uint2*)wob, 262144);
  cast_kernel<<<4096, 256, 0, stream>>>((const float4*)W1, (uint2*)w1b, 1048576);
  cast_kernel<<<4096, 256, 0, stream>>>((const float4*)W2, (uint2*)w2b, 1048576);

  for (int l = 0; l < L_; ++l) {
    // fused K-proj (z=0, row-major) + V-proj (z=1, vT transposed)
    gemm256_kernel<128,0,3><<<dim3(2, 128, 2), 512, 0, stream>>>(
        xb, wkb + (size_t)l * 262144, bk + l * 512,
        yb, wvb + (size_t)l * 262144, bv + l * 512,
        kqb, vtb, 512, 512, 512);
    fattn_kernel<<<1024, 256, 0, stream>>>(kqb, vtb, frr, ctxb);
    gemm256_kernel<128,0,0><<<dim3(2, 128, 1), 512, 0, stream>>>(
        ctxb, wob + (size_t)l * 262144, bo + l * 512,
        nullptr, nullptr, nullptr, obf, nullptr, 512, 512, 512);
    ln_kernel<1><<<4096, 256, 0, stream>>>((const float4*)xf, (const uint4*)obf, nullptr,
                                           g1 + l * 512, be1 + l * 512,
                                           (float4*)xf, (uint2*)xb);
    gemm256_kernel<256,1,0><<<dim3(8, 64, 1), 512, 0, stream>>>(
        xb, w1b + (size_t)l * 1048576, b1 + l * 2048,
        nullptr, nullptr, nullptr, hb, nullptr, 2048, 512, 512);
    gemm256_kernel<256,0,0><<<dim3(2, 64, 2), 512, 0, stream>>>(
        hb, w2b + (size_t)l * 1048576, b2 + l * 512,
        nullptr, nullptr, nullptr, pf0, pf1, 512, 2048, 1024);
    float* lnout = (l == L_ - 1) ? (float*)d_out : xf;
    ln_kernel<2><<<4096, 256, 0, stream>>>((const float4*)xf, (const uint4*)pf0,
                                           (const uint4*)pf1,
                                           g2 + l * 512, be2 + l * 512,
                                           (float4*)lnout, (uint2*)xb);
  }
}